// Round 9
// baseline (138.888 us; speedup 1.0000x reference)
//
#include <hip/hip_runtime.h>

// ---------------------------------------------------------------------------
// DagLinkExtractor: B=8, N=1024, HID=1024, NH=4, HD=256
// out[b,i,j] = log Σ_h P[b,h,i,j]·ec[b,h,i]   (alive), else -1e9
//   P = exp(s), s = (Q_h . K_h)/16  (1/16 folded into stored Q)
//   ec[b,h,i] = exp(log_gate) / Z,  Z = Σ_{valid j>i} exp(s)
// k_sc: score pass AS A GEMM — clone of the proven 4-phase 256²-tile k_gemm
// (NT=4, stride 256), upper-tri tiles only; epilogue = exp -> Pe + Z partials.
// ---------------------------------------------------------------------------

typedef __attribute__((ext_vector_type(8))) short bf16x8;
typedef __attribute__((ext_vector_type(4))) short bf16x4;
typedef __attribute__((ext_vector_type(4))) float f32x4;

#define LB __launch_bounds__(256)

__device__ __forceinline__ short f2bf(float f) {
    unsigned u = __float_as_uint(f);
    u += 0x7fffu + ((u >> 16) & 1u);   // RNE
    return (short)(u >> 16);
}
__device__ __forceinline__ float bf2f(short s) {
    return __uint_as_float(((unsigned)(unsigned short)s) << 16);
}

__device__ __forceinline__ void gld16(const void* g, void* l) {
    __builtin_amdgcn_global_load_lds(
        (const __attribute__((address_space(1))) unsigned int*)g,
        (__attribute__((address_space(3))) unsigned int*)l, 16, 0, 0);
}

// ---- 1. fused: Xb = bf16(features), lgA = log_softmax(features@Wg+bg) -------
__global__ LB void k_prep(const float* __restrict__ feat, const float* __restrict__ Wg,
                          const float* __restrict__ bg, short* __restrict__ Xb,
                          float* __restrict__ lgA) {
    int row = blockIdx.x * 4 + (threadIdx.x >> 6);
    int lane = threadIdx.x & 63;
    const float* f = feat + (size_t)row * 1024;
    float g0 = 0.f, g1 = 0.f, g2 = 0.f, g3 = 0.f;
#pragma unroll
    for (int tt = 0; tt < 4; ++tt) {
        int k = tt * 256 + lane * 4;
        float4 x = *(const float4*)&f[k];
        float4 w0 = *(const float4*)&Wg[(k + 0) * 4];
        float4 w1 = *(const float4*)&Wg[(k + 1) * 4];
        float4 w2 = *(const float4*)&Wg[(k + 2) * 4];
        float4 w3 = *(const float4*)&Wg[(k + 3) * 4];
        g0 += x.x * w0.x + x.y * w1.x + x.z * w2.x + x.w * w3.x;
        g1 += x.x * w0.y + x.y * w1.y + x.z * w2.y + x.w * w3.y;
        g2 += x.x * w0.z + x.y * w1.z + x.z * w2.z + x.w * w3.z;
        g3 += x.x * w0.w + x.y * w1.w + x.z * w2.w + x.w * w3.w;
        bf16x4 xv;
        xv[0] = f2bf(x.x); xv[1] = f2bf(x.y); xv[2] = f2bf(x.z); xv[3] = f2bf(x.w);
        *(bf16x4*)&Xb[(size_t)row * 1024 + k] = xv;
    }
#pragma unroll
    for (int off = 32; off; off >>= 1) {
        g0 += __shfl_xor(g0, off); g1 += __shfl_xor(g1, off);
        g2 += __shfl_xor(g2, off); g3 += __shfl_xor(g3, off);
    }
    g0 += bg[0]; g1 += bg[1]; g2 += bg[2]; g3 += bg[3];
    float m = fmaxf(fmaxf(g0, g1), fmaxf(g2, g3));
    float s = __expf(g0 - m) + __expf(g1 - m) + __expf(g2 - m) + __expf(g3 - m);
    float ls = m + __logf(s);
    if (lane == 0) {
        float4 o = {g0 - ls, g1 - ls, g2 - ls, g3 - ls};
        *(float4*)&lgA[row * 4] = o;
    }
}

// ---- 2. Wt[n][k] = W[k][n] (bf16), n<1024 -> Wq, else Wk --------------------
__global__ LB void k_cvt_w(const float* __restrict__ Wq, const float* __restrict__ Wk,
                           short* __restrict__ Wt) {
    __shared__ float tile[32][33];
    int n0 = blockIdx.x * 32, k0 = blockIdx.y * 32;
    const float* W = (n0 < 1024) ? Wq : Wk;
    int nb = n0 & 1023;
    int tx = threadIdx.x, ty = threadIdx.y;
#pragma unroll
    for (int jj = 0; jj < 4; ++jj) {
        int k = ty + jj * 8;
        tile[k][tx] = W[(size_t)(k0 + k) * 1024 + nb + tx];
    }
    __syncthreads();
#pragma unroll
    for (int jj = 0; jj < 4; ++jj) {
        int n = ty + jj * 8;
        Wt[(size_t)(n0 + n) * 1024 + k0 + tx] = f2bf(tile[tx][n]);
    }
}

// ---- 3. GEMM 256x256 tile, BK=64, 4-quadrant-phase, counted vmcnt -----------
__global__ __launch_bounds__(512, 2) void k_gemm(const short* __restrict__ Xb,
                                                 const short* __restrict__ Wt,
                                                 const float* __restrict__ bq,
                                                 const float* __restrict__ bk,
                                                 short* __restrict__ Qb,
                                                 short* __restrict__ Kb) {
    __shared__ short As[2][16384];                 // 2 x 32 KB: [256][64] bf16
    __shared__ short Bs[2][16384];
    const int t = threadIdx.x;
    const int lane = t & 63, wid = t >> 6;
    const int wr = wid >> 2, wc = wid & 3;         // 2 x 4 waves
    const int lr = lane & 15, lg4 = lane >> 4;
    const int wgid = (blockIdx.x & 7) * 32 + (blockIdx.x >> 3);
    const int mt = wgid >> 3, nt = wgid & 7;
    const int m0t = mt * 256, n0t = nt * 256;

    f32x4 acc[8][4] = {};

#define STAGE_A(q, k1, dst)                                                     \
    { int s_ = (q) * 512 + t; int tr_ = s_ >> 3, sl_ = s_ & 7;                  \
      gld16(&Xb[(size_t)(m0t + tr_) * 1024 + (k1) + ((sl_ ^ (tr_ & 7)) * 8)],   \
            &(dst)[s_ * 8]); }
#define STAGE_B(q, k1, dst)                                                     \
    { int s_ = (q) * 512 + t; int tr_ = s_ >> 3, sl_ = s_ & 7;                  \
      gld16(&Wt[(size_t)(n0t + tr_) * 1024 + (k1) + ((sl_ ^ (tr_ & 7)) * 8)],   \
            &(dst)[s_ * 8]); }

    {
        short* Ad = As[0]; short* Bd = Bs[0];
        STAGE_A(0, 0, Ad); STAGE_A(1, 0, Ad); STAGE_A(2, 0, Ad); STAGE_A(3, 0, Ad);
        STAGE_B(0, 0, Bd); STAGE_B(1, 0, Bd); STAGE_B(2, 0, Bd); STAGE_B(3, 0, Bd);
    }
    asm volatile("s_waitcnt vmcnt(0)" ::: "memory");
    __builtin_amdgcn_sched_barrier(0);
    __builtin_amdgcn_s_barrier();

    for (int kt = 0; kt < 16; ++kt) {
        const int cur = kt & 1;
        const short* Ac = As[cur];
        const short* Bc = Bs[cur];
        short* Ad = As[cur ^ 1];
        short* Bd = Bs[cur ^ 1];
        const int k1 = (kt + 1) * 64;
#pragma unroll
        for (int p = 0; p < 4; ++p) {
            const int mh = p >> 1, nh = p & 1;
            bf16x8 aF[4][2], bF[2][2];
#pragma unroll
            for (int m = 0; m < 4; ++m)
#pragma unroll
                for (int ks = 0; ks < 2; ++ks) {
                    int row = wr * 128 + mh * 64 + m * 16 + lr;
                    aF[m][ks] = *(const bf16x8*)
                        &Ac[row * 64 + (((ks * 4 + lg4) ^ (lr & 7)) * 8)];
                }
#pragma unroll
            for (int n = 0; n < 2; ++n)
#pragma unroll
                for (int ks = 0; ks < 2; ++ks) {
                    int row = wc * 64 + (nh * 2 + n) * 16 + lr;
                    bF[n][ks] = *(const bf16x8*)
                        &Bc[row * 64 + (((ks * 4 + lg4) ^ (lr & 7)) * 8)];
                }
            if (kt < 15) {
                if (p == 0)      { STAGE_A(0, k1, Ad); STAGE_A(2, k1, Ad); }
                else if (p == 1) { STAGE_B(0, k1, Bd); STAGE_B(1, k1, Bd); }
                else if (p == 2) { STAGE_B(2, k1, Bd); STAGE_B(3, k1, Bd); }
                else             { STAGE_A(1, k1, Ad); STAGE_A(3, k1, Ad); }
            }
            if (p == 1) {
                if (kt < 15) asm volatile("s_waitcnt vmcnt(4)" ::: "memory");
                else         asm volatile("s_waitcnt vmcnt(0)" ::: "memory");
            } else if (p == 3 && kt < 15) {
                asm volatile("s_waitcnt vmcnt(2)" ::: "memory");
            }
            __builtin_amdgcn_sched_barrier(0);
            __builtin_amdgcn_s_barrier();
            asm volatile("s_waitcnt lgkmcnt(0)" ::: "memory");
            __builtin_amdgcn_sched_barrier(0);
            __builtin_amdgcn_s_setprio(1);
#pragma unroll
            for (int ks = 0; ks < 2; ++ks)
#pragma unroll
                for (int m = 0; m < 4; ++m)
#pragma unroll
                    for (int n = 0; n < 2; ++n)
                        acc[mh * 4 + m][nh * 2 + n] =
                            __builtin_amdgcn_mfma_f32_16x16x32_bf16(
                                aF[m][ks], bF[n][ks], acc[mh * 4 + m][nh * 2 + n],
                                0, 0, 0);
            __builtin_amdgcn_s_setprio(0);
        }
    }
#undef STAGE_A
#undef STAGE_B

#pragma unroll
    for (int mf = 0; mf < 8; ++mf) {
#pragma unroll
        for (int nf = 0; nf < 4; ++nf) {
            int col = n0t + wc * 64 + nf * 16 + lr;
            float bias = (col < 1024) ? bq[col] : bk[col - 1024];
            float scale = (col < 1024) ? 0.0625f : 1.0f;
            short* dst = (col < 1024) ? Qb : Kb;
            int h = (col >> 8) & 3, d = col & 255;
#pragma unroll
            for (int r = 0; r < 4; ++r) {
                int rowg = m0t + wr * 128 + mf * 16 + lg4 * 4 + r;
                int b_ = rowg >> 10, i_ = rowg & 1023;
                float v = (acc[mf][nf][r] + bias) * scale;
                dst[((size_t)(b_ * 4 + h) * 1024 + i_) * 256 + d] = f2bf(v);
            }
        }
    }
}

// ---- 4. k_sc: score GEMM s = Qb @ Kb^T per bh, upper-tri 256² tiles ---------
// grid 320 = 32 bh x 10 tiles (jt>=it), 512 thr; XCD-chunked (4 bh per XCD).
// Epilogue: Pe[bh][i][j] = bf16(exp(s)); Zp[jt*4+wc][bh][i] masked row sums.
__global__ __launch_bounds__(512, 2) void k_sc(const short* __restrict__ Qb,
                                               const short* __restrict__ Kb,
                                               const int* __restrict__ vm,
                                               short* __restrict__ Pe,
                                               float* __restrict__ Zp) {
    __shared__ short As[2][16384];                 // [256 i][64 d] bf16
    __shared__ short Bs[2][16384];                 // [256 j][64 d] bf16
    const int t = threadIdx.x;
    const int lane = t & 63, wid = t >> 6;
    const int wr = wid >> 2, wc = wid & 3;
    const int lr = lane & 15, lg4 = lane >> 4;
    const int gidx = (blockIdx.x & 7) * 40 + (blockIdx.x >> 3);   // XCD-chunked
    const int bh = gidx / 10, tt = gidx % 10;
    const int ITt[10] = {0, 0, 0, 0, 1, 1, 1, 2, 2, 3};
    const int JTt[10] = {0, 1, 2, 3, 1, 2, 3, 2, 3, 3};
    const int it = ITt[tt], jt = JTt[tt];
    const int b = bh >> 2;
    const short* Qp = Qb + ((size_t)bh << 18);     // [1024][256]
    const short* Kp = Kb + ((size_t)bh << 18);

    f32x4 acc[8][4] = {};

#define STAGE_A(q, k1, dst)                                                     \
    { int s_ = (q) * 512 + t; int tr_ = s_ >> 3, sl_ = s_ & 7;                  \
      gld16(&Qp[(size_t)(it * 256 + tr_) * 256 + (k1) + ((sl_ ^ (tr_ & 7)) * 8)], \
            &(dst)[s_ * 8]); }
#define STAGE_B(q, k1, dst)                                                     \
    { int s_ = (q) * 512 + t; int tr_ = s_ >> 3, sl_ = s_ & 7;                  \
      gld16(&Kp[(size_t)(jt * 256 + tr_) * 256 + (k1) + ((sl_ ^ (tr_ & 7)) * 8)], \
            &(dst)[s_ * 8]); }

    {
        short* Ad = As[0]; short* Bd = Bs[0];
        STAGE_A(0, 0, Ad); STAGE_A(1, 0, Ad); STAGE_A(2, 0, Ad); STAGE_A(3, 0, Ad);
        STAGE_B(0, 0, Bd); STAGE_B(1, 0, Bd); STAGE_B(2, 0, Bd); STAGE_B(3, 0, Bd);
    }
    asm volatile("s_waitcnt vmcnt(0)" ::: "memory");
    __builtin_amdgcn_sched_barrier(0);
    __builtin_amdgcn_s_barrier();

    for (int kt = 0; kt < 4; ++kt) {
        const int cur = kt & 1;
        const short* Ac = As[cur];
        const short* Bc = Bs[cur];
        short* Ad = As[cur ^ 1];
        short* Bd = Bs[cur ^ 1];
        const int k1 = (kt + 1) * 64;
#pragma unroll
        for (int p = 0; p < 4; ++p) {
            const int mh = p >> 1, nh = p & 1;
            bf16x8 aF[4][2], bF[2][2];
#pragma unroll
            for (int m = 0; m < 4; ++m)
#pragma unroll
                for (int ks = 0; ks < 2; ++ks) {
                    int row = wr * 128 + mh * 64 + m * 16 + lr;
                    aF[m][ks] = *(const bf16x8*)
                        &Ac[row * 64 + (((ks * 4 + lg4) ^ (lr & 7)) * 8)];
                }
#pragma unroll
            for (int n = 0; n < 2; ++n)
#pragma unroll
                for (int ks = 0; ks < 2; ++ks) {
                    int row = wc * 64 + (nh * 2 + n) * 16 + lr;
                    bF[n][ks] = *(const bf16x8*)
                        &Bc[row * 64 + (((ks * 4 + lg4) ^ (lr & 7)) * 8)];
                }
            if (kt < 3) {
                if (p == 0)      { STAGE_A(0, k1, Ad); STAGE_A(2, k1, Ad); }
                else if (p == 1) { STAGE_B(0, k1, Bd); STAGE_B(1, k1, Bd); }
                else if (p == 2) { STAGE_B(2, k1, Bd); STAGE_B(3, k1, Bd); }
                else             { STAGE_A(1, k1, Ad); STAGE_A(3, k1, Ad); }
            }
            if (p == 1) {
                if (kt < 3) asm volatile("s_waitcnt vmcnt(4)" ::: "memory");
                else        asm volatile("s_waitcnt vmcnt(0)" ::: "memory");
            } else if (p == 3 && kt < 3) {
                asm volatile("s_waitcnt vmcnt(2)" ::: "memory");
            }
            __builtin_amdgcn_sched_barrier(0);
            __builtin_amdgcn_s_barrier();
            asm volatile("s_waitcnt lgkmcnt(0)" ::: "memory");
            __builtin_amdgcn_sched_barrier(0);
            __builtin_amdgcn_s_setprio(1);
#pragma unroll
            for (int ks = 0; ks < 2; ++ks)
#pragma unroll
                for (int m = 0; m < 4; ++m)
#pragma unroll
                    for (int n = 0; n < 2; ++n)
                        acc[mh * 4 + m][nh * 2 + n] =
                            __builtin_amdgcn_mfma_f32_16x16x32_bf16(
                                aF[m][ks], bF[n][ks], acc[mh * 4 + m][nh * 2 + n],
                                0, 0, 0);
            __builtin_amdgcn_s_setprio(0);
        }
    }
#undef STAGE_A
#undef STAGE_B

    // epilogue: e = exp(s) -> Pe; masked row-sum partials -> Zp[jt*4+wc]
    short* Pp = Pe + ((size_t)bh << 20);
    const int rowbase = it * 256 + wr * 128;
    const int colbase = jt * 256 + wc * 64;
    int vmv[4];
#pragma unroll
    for (int nf = 0; nf < 4; ++nf)
        vmv[nf] = vm[(b << 10) + colbase + nf * 16 + lr];
    float zacc[8][4] = {};
#pragma unroll
    for (int mf = 0; mf < 8; ++mf) {
#pragma unroll
        for (int nf = 0; nf < 4; ++nf) {
            const int col = colbase + nf * 16 + lr;
#pragma unroll
            for (int r = 0; r < 4; ++r) {
                const int row = rowbase + mf * 16 + lg4 * 4 + r;
                float e = __expf(acc[mf][nf][r]);
                Pp[(size_t)row * 1024 + col] = f2bf(e);
                zacc[mf][r] += (vmv[nf] && (col > row)) ? e : 0.f;
            }
        }
    }
#pragma unroll
    for (int mf = 0; mf < 8; ++mf)
#pragma unroll
        for (int r = 0; r < 4; ++r) {
            zacc[mf][r] += __shfl_xor(zacc[mf][r], 1);
            zacc[mf][r] += __shfl_xor(zacc[mf][r], 2);
            zacc[mf][r] += __shfl_xor(zacc[mf][r], 4);
            zacc[mf][r] += __shfl_xor(zacc[mf][r], 8);
        }
    if (lr == 0) {
        float* Zs = Zp + (size_t)(jt * 4 + wc) * 32768 + bh * 1024;
#pragma unroll
        for (int mf = 0; mf < 8; ++mf)
#pragma unroll
            for (int r = 0; r < 4; ++r)
                Zs[rowbase + mf * 16 + lg4 * 4 + r] = zacc[mf][r];
    }
}

// ---- 5. ecF[(b,i)][h] = exp(lg)/Z; sum only written Zp slices (jt>=i>>8) ----
__global__ LB void k_c(const float* __restrict__ lgA, const float* __restrict__ Zp,
                       float* __restrict__ ecF) {
    int idx = blockIdx.x * 256 + threadIdx.x;      // 8192 = b*1024+i
    int b = idx >> 10, i = idx & 1023;
    int sl0 = (i >> 8) * 4;
    float4 lg = *(const float4*)&lgA[idx * 4];
    float4 o;
#pragma unroll
    for (int h = 0; h < 4; ++h) {
        int base = (b * 4 + h) * 1024 + i;
        float Zv = 0.f;
        for (int sl = sl0; sl < 16; ++sl) Zv += Zp[sl * 32768 + base];
        float lgv = (h == 0) ? lg.x : (h == 1) ? lg.y : (h == 2) ? lg.z : lg.w;
        float e = (Zv > 0.f) ? __expf(lgv) / Zv : 0.f;
        if (h == 0) o.x = e; else if (h == 1) o.y = e;
        else if (h == 2) o.z = e; else o.w = e;
    }
    *(float4*)&ecF[idx * 4] = o;
}

// ---- 6. streaming epilogue: out = alive ? log(dot(P, ec)) : -1e9 ------------
__global__ LB void k_final(const short* __restrict__ Pe, const int* __restrict__ vm,
                           const float* __restrict__ ecF, float* __restrict__ out) {
    const int blk = blockIdx.x;                    // b*1024 + i
    const int b = blk >> 10, i = blk & 1023;
    const int j0 = threadIdx.x * 4;
    float4 o = {-1.0e9f, -1.0e9f, -1.0e9f, -1.0e9f};
    if (j0 + 3 > i) {
        float4 ec = *(const float4*)&ecF[blk * 4];
        int4 v4 = *(const int4*)&vm[(b << 10) + j0];
        const size_t off = ((size_t)(i) << 10) + j0;
        bf16x4 p0 = *(const bf16x4*)&Pe[(((size_t)(b * 4 + 0)) << 20) + off];
        bf16x4 p1 = *(const bf16x4*)&Pe[(((size_t)(b * 4 + 1)) << 20) + off];
        bf16x4 p2 = *(const bf16x4*)&Pe[(((size_t)(b * 4 + 2)) << 20) + off];
        bf16x4 p3 = *(const bf16x4*)&Pe[(((size_t)(b * 4 + 3)) << 20) + off];
        float a0 = bf2f(p0[0]) * ec.x + bf2f(p1[0]) * ec.y
                 + bf2f(p2[0]) * ec.z + bf2f(p3[0]) * ec.w;
        float a1 = bf2f(p0[1]) * ec.x + bf2f(p1[1]) * ec.y
                 + bf2f(p2[1]) * ec.z + bf2f(p3[1]) * ec.w;
        float a2 = bf2f(p0[2]) * ec.x + bf2f(p1[2]) * ec.y
                 + bf2f(p2[2]) * ec.z + bf2f(p3[2]) * ec.w;
        float a3 = bf2f(p0[3]) * ec.x + bf2f(p1[3]) * ec.y
                 + bf2f(p2[3]) * ec.z + bf2f(p3[3]) * ec.w;
        o.x = (v4.x && (j0 + 0 > i)) ? __logf(a0) : -1.0e9f;
        o.y = (v4.y && (j0 + 1 > i)) ? __logf(a1) : -1.0e9f;
        o.z = (v4.z && (j0 + 2 > i)) ? __logf(a2) : -1.0e9f;
        o.w = (v4.w && (j0 + 3 > i)) ? __logf(a3) : -1.0e9f;
    }
    *(float4*)&out[((size_t)blk << 10) + j0] = o;
}

// ---------------------------------------------------------------------------
extern "C" void kernel_launch(void* const* d_in, const int* in_sizes, int n_in,
                              void* d_out, int out_size, void* d_ws, size_t ws_size,
                              hipStream_t stream) {
    const float* features = (const float*)d_in[0];
    const int*   vmask    = (const int*)d_in[1];
    const float* Wq       = (const float*)d_in[2];
    const float* bq       = (const float*)d_in[3];
    const float* Wk       = (const float*)d_in[4];
    const float* bk       = (const float*)d_in[5];
    const float* Wg       = (const float*)d_in[6];
    const float* bg       = (const float*)d_in[7];
    float* out = (float*)d_out;

    // ws carve (~103 MB peak). Pe overlaps Xb+Wt (dead before k_sc).
    short* Pe = (short*)d_ws;                  // [32 bh][1024 i][1024 j] bf16 = 67 MB
    short* Xb = (short*)d_ws;                  // [8192][1024] bf16 (dead after k_gemm)
    short* Wt = Xb + 8388608;                  // [2048][1024] bf16 (dead after k_gemm)
    short* Qb = Pe + 33554432;                 // [32 bh][1024 i][256 d] bf16 (scaled 1/16)
    short* Kb = Qb + 8388608;                  // [32 bh][1024 j][256 d] bf16
    float* lgA = (float*)(Kb + 8388608);       // [8192][4]
    float* Zp  = lgA + 32768;                  // [16 slice][32 bh][1024 i]
    float* ecF = Zp + 524288;                  // [8192][4]

    k_prep<<<2048, 256, 0, stream>>>(features, Wg, bg, Xb, lgA);
    k_cvt_w<<<dim3(64, 32), dim3(32, 8), 0, stream>>>(Wq, Wk, Wt);
    k_gemm<<<256, 512, 0, stream>>>(Xb, Wt, bq, bk, Qb, Kb);
    k_sc<<<320, 512, 0, stream>>>(Qb, Kb, vmask, Pe, Zp);
    k_c<<<32, 256, 0, stream>>>(lgA, Zp, ecF);
    k_final<<<8192, 256, 0, stream>>>(Pe, vmask, ecF, out);
}

// Round 10
// 119.663 us; speedup vs baseline: 1.1607x; 1.1607x over previous
//
#include <hip/hip_runtime.h>

// ---------------------------------------------------------------------------
// DagLinkExtractor: B=8, N=1024, HID=1024, NH=4, HD=256
// out[b,i,j] = log Σ_h P[b,h,i,j]·ec[b,h,i]   (alive), else -1e9
//   P = exp(s), s = (Q_h . K_h)/16  (1/16 folded into stored Q)
//   ec[b,h,i] = exp(log_gate) / Z,  Z = Σ_{valid j>i} exp(s)
// k_sc: score GEMM (proven 4-phase 256² structure); epilogue transposes
// exp(acc) through per-wave LDS regions -> 16B/lane coalesced Pe stores.
// ---------------------------------------------------------------------------

typedef __attribute__((ext_vector_type(8))) short bf16x8;
typedef __attribute__((ext_vector_type(4))) short bf16x4;
typedef __attribute__((ext_vector_type(4))) float f32x4;

#define LB __launch_bounds__(256)

__device__ __forceinline__ short f2bf(float f) {
    unsigned u = __float_as_uint(f);
    u += 0x7fffu + ((u >> 16) & 1u);   // RNE
    return (short)(u >> 16);
}
__device__ __forceinline__ float bf2f(short s) {
    return __uint_as_float(((unsigned)(unsigned short)s) << 16);
}

__device__ __forceinline__ void gld16(const void* g, void* l) {
    __builtin_amdgcn_global_load_lds(
        (const __attribute__((address_space(1))) unsigned int*)g,
        (__attribute__((address_space(3))) unsigned int*)l, 16, 0, 0);
}

// ---- 1. fused: Xb = bf16(features), lgA = log_softmax(features@Wg+bg) -------
__global__ LB void k_prep(const float* __restrict__ feat, const float* __restrict__ Wg,
                          const float* __restrict__ bg, short* __restrict__ Xb,
                          float* __restrict__ lgA) {
    int row = blockIdx.x * 4 + (threadIdx.x >> 6);
    int lane = threadIdx.x & 63;
    const float* f = feat + (size_t)row * 1024;
    float g0 = 0.f, g1 = 0.f, g2 = 0.f, g3 = 0.f;
#pragma unroll
    for (int tt = 0; tt < 4; ++tt) {
        int k = tt * 256 + lane * 4;
        float4 x = *(const float4*)&f[k];
        float4 w0 = *(const float4*)&Wg[(k + 0) * 4];
        float4 w1 = *(const float4*)&Wg[(k + 1) * 4];
        float4 w2 = *(const float4*)&Wg[(k + 2) * 4];
        float4 w3 = *(const float4*)&Wg[(k + 3) * 4];
        g0 += x.x * w0.x + x.y * w1.x + x.z * w2.x + x.w * w3.x;
        g1 += x.x * w0.y + x.y * w1.y + x.z * w2.y + x.w * w3.y;
        g2 += x.x * w0.z + x.y * w1.z + x.z * w2.z + x.w * w3.z;
        g3 += x.x * w0.w + x.y * w1.w + x.z * w2.w + x.w * w3.w;
        bf16x4 xv;
        xv[0] = f2bf(x.x); xv[1] = f2bf(x.y); xv[2] = f2bf(x.z); xv[3] = f2bf(x.w);
        *(bf16x4*)&Xb[(size_t)row * 1024 + k] = xv;
    }
#pragma unroll
    for (int off = 32; off; off >>= 1) {
        g0 += __shfl_xor(g0, off); g1 += __shfl_xor(g1, off);
        g2 += __shfl_xor(g2, off); g3 += __shfl_xor(g3, off);
    }
    g0 += bg[0]; g1 += bg[1]; g2 += bg[2]; g3 += bg[3];
    float m = fmaxf(fmaxf(g0, g1), fmaxf(g2, g3));
    float s = __expf(g0 - m) + __expf(g1 - m) + __expf(g2 - m) + __expf(g3 - m);
    float ls = m + __logf(s);
    if (lane == 0) {
        float4 o = {g0 - ls, g1 - ls, g2 - ls, g3 - ls};
        *(float4*)&lgA[row * 4] = o;
    }
}

// ---- 2. Wt[n][k] = W[k][n] (bf16), n<1024 -> Wq, else Wk --------------------
__global__ LB void k_cvt_w(const float* __restrict__ Wq, const float* __restrict__ Wk,
                           short* __restrict__ Wt) {
    __shared__ float tile[32][33];
    int n0 = blockIdx.x * 32, k0 = blockIdx.y * 32;
    const float* W = (n0 < 1024) ? Wq : Wk;
    int nb = n0 & 1023;
    int tx = threadIdx.x, ty = threadIdx.y;
#pragma unroll
    for (int jj = 0; jj < 4; ++jj) {
        int k = ty + jj * 8;
        tile[k][tx] = W[(size_t)(k0 + k) * 1024 + nb + tx];
    }
    __syncthreads();
#pragma unroll
    for (int jj = 0; jj < 4; ++jj) {
        int n = ty + jj * 8;
        Wt[(size_t)(n0 + n) * 1024 + k0 + tx] = f2bf(tile[tx][n]);
    }
}

// ---- 3. GEMM 256x256 tile, BK=64, 4-quadrant-phase, counted vmcnt -----------
__global__ __launch_bounds__(512, 2) void k_gemm(const short* __restrict__ Xb,
                                                 const short* __restrict__ Wt,
                                                 const float* __restrict__ bq,
                                                 const float* __restrict__ bk,
                                                 short* __restrict__ Qb,
                                                 short* __restrict__ Kb) {
    __shared__ short As[2][16384];                 // 2 x 32 KB: [256][64] bf16
    __shared__ short Bs[2][16384];
    const int t = threadIdx.x;
    const int lane = t & 63, wid = t >> 6;
    const int wr = wid >> 2, wc = wid & 3;         // 2 x 4 waves
    const int lr = lane & 15, lg4 = lane >> 4;
    const int wgid = (blockIdx.x & 7) * 32 + (blockIdx.x >> 3);
    const int mt = wgid >> 3, nt = wgid & 7;
    const int m0t = mt * 256, n0t = nt * 256;

    f32x4 acc[8][4] = {};

#define STAGE_A(q, k1, dst)                                                     \
    { int s_ = (q) * 512 + t; int tr_ = s_ >> 3, sl_ = s_ & 7;                  \
      gld16(&Xb[(size_t)(m0t + tr_) * 1024 + (k1) + ((sl_ ^ (tr_ & 7)) * 8)],   \
            &(dst)[s_ * 8]); }
#define STAGE_B(q, k1, dst)                                                     \
    { int s_ = (q) * 512 + t; int tr_ = s_ >> 3, sl_ = s_ & 7;                  \
      gld16(&Wt[(size_t)(n0t + tr_) * 1024 + (k1) + ((sl_ ^ (tr_ & 7)) * 8)],   \
            &(dst)[s_ * 8]); }

    {
        short* Ad = As[0]; short* Bd = Bs[0];
        STAGE_A(0, 0, Ad); STAGE_A(1, 0, Ad); STAGE_A(2, 0, Ad); STAGE_A(3, 0, Ad);
        STAGE_B(0, 0, Bd); STAGE_B(1, 0, Bd); STAGE_B(2, 0, Bd); STAGE_B(3, 0, Bd);
    }
    asm volatile("s_waitcnt vmcnt(0)" ::: "memory");
    __builtin_amdgcn_sched_barrier(0);
    __builtin_amdgcn_s_barrier();

    for (int kt = 0; kt < 16; ++kt) {
        const int cur = kt & 1;
        const short* Ac = As[cur];
        const short* Bc = Bs[cur];
        short* Ad = As[cur ^ 1];
        short* Bd = Bs[cur ^ 1];
        const int k1 = (kt + 1) * 64;
#pragma unroll
        for (int p = 0; p < 4; ++p) {
            const int mh = p >> 1, nh = p & 1;
            bf16x8 aF[4][2], bF[2][2];
#pragma unroll
            for (int m = 0; m < 4; ++m)
#pragma unroll
                for (int ks = 0; ks < 2; ++ks) {
                    int row = wr * 128 + mh * 64 + m * 16 + lr;
                    aF[m][ks] = *(const bf16x8*)
                        &Ac[row * 64 + (((ks * 4 + lg4) ^ (lr & 7)) * 8)];
                }
#pragma unroll
            for (int n = 0; n < 2; ++n)
#pragma unroll
                for (int ks = 0; ks < 2; ++ks) {
                    int row = wc * 64 + (nh * 2 + n) * 16 + lr;
                    bF[n][ks] = *(const bf16x8*)
                        &Bc[row * 64 + (((ks * 4 + lg4) ^ (lr & 7)) * 8)];
                }
            if (kt < 15) {
                if (p == 0)      { STAGE_A(0, k1, Ad); STAGE_A(2, k1, Ad); }
                else if (p == 1) { STAGE_B(0, k1, Bd); STAGE_B(1, k1, Bd); }
                else if (p == 2) { STAGE_B(2, k1, Bd); STAGE_B(3, k1, Bd); }
                else             { STAGE_A(1, k1, Ad); STAGE_A(3, k1, Ad); }
            }
            if (p == 1) {
                if (kt < 15) asm volatile("s_waitcnt vmcnt(4)" ::: "memory");
                else         asm volatile("s_waitcnt vmcnt(0)" ::: "memory");
            } else if (p == 3 && kt < 15) {
                asm volatile("s_waitcnt vmcnt(2)" ::: "memory");
            }
            __builtin_amdgcn_sched_barrier(0);
            __builtin_amdgcn_s_barrier();
            asm volatile("s_waitcnt lgkmcnt(0)" ::: "memory");
            __builtin_amdgcn_sched_barrier(0);
            __builtin_amdgcn_s_setprio(1);
#pragma unroll
            for (int ks = 0; ks < 2; ++ks)
#pragma unroll
                for (int m = 0; m < 4; ++m)
#pragma unroll
                    for (int n = 0; n < 2; ++n)
                        acc[mh * 4 + m][nh * 2 + n] =
                            __builtin_amdgcn_mfma_f32_16x16x32_bf16(
                                aF[m][ks], bF[n][ks], acc[mh * 4 + m][nh * 2 + n],
                                0, 0, 0);
            __builtin_amdgcn_s_setprio(0);
        }
    }
#undef STAGE_A
#undef STAGE_B

#pragma unroll
    for (int mf = 0; mf < 8; ++mf) {
#pragma unroll
        for (int nf = 0; nf < 4; ++nf) {
            int col = n0t + wc * 64 + nf * 16 + lr;
            float bias = (col < 1024) ? bq[col] : bk[col - 1024];
            float scale = (col < 1024) ? 0.0625f : 1.0f;
            short* dst = (col < 1024) ? Qb : Kb;
            int h = (col >> 8) & 3, d = col & 255;
#pragma unroll
            for (int r = 0; r < 4; ++r) {
                int rowg = m0t + wr * 128 + mf * 16 + lg4 * 4 + r;
                int b_ = rowg >> 10, i_ = rowg & 1023;
                float v = (acc[mf][nf][r] + bias) * scale;
                dst[((size_t)(b_ * 4 + h) * 1024 + i_) * 256 + d] = f2bf(v);
            }
        }
    }
}

// ---- 4. k_sc: score GEMM s = Qb @ Kb^T per bh, upper-tri 256² tiles ---------
// grid 320 = 32 bh x 10 tiles (jt>=it), 512 thr; XCD-chunked (4 bh per XCD).
// Epilogue: per-wave LDS transpose (stride-66) -> coalesced 16B/lane Pe stores;
// Zp[jt*4+wc][bh][i] masked row sums.
__global__ __launch_bounds__(512, 2) void k_sc(const short* __restrict__ Qb,
                                               const short* __restrict__ Kb,
                                               const int* __restrict__ vm,
                                               short* __restrict__ Pe,
                                               float* __restrict__ Zp) {
    __shared__ short SMEM[65536];                  // 128 KB: staging + epilogue
    short* As0 = SMEM;                             // [2][16384]
    short* Bs0 = SMEM + 32768;
    const int t = threadIdx.x;
    const int lane = t & 63, wid = t >> 6;
    const int wr = wid >> 2, wc = wid & 3;
    const int lr = lane & 15, lg4 = lane >> 4;
    const int gidx = (blockIdx.x & 7) * 40 + (blockIdx.x >> 3);   // XCD-chunked
    const int bh = gidx / 10, tt = gidx % 10;
    const int it = (tt < 4) ? 0 : (tt < 7) ? 1 : (tt < 9) ? 2 : 3;
    const int jt = tt - ((it == 0) ? 0 : (it == 1) ? 3 : (it == 2) ? 5 : 6);
    const int b = bh >> 2;
    const short* Qp = Qb + ((size_t)bh << 18);     // [1024][256]
    const short* Kp = Kb + ((size_t)bh << 18);

    f32x4 acc[8][4] = {};

#define STAGE_A(q, k1, dst)                                                     \
    { int s_ = (q) * 512 + t; int tr_ = s_ >> 3, sl_ = s_ & 7;                  \
      gld16(&Qp[(size_t)(it * 256 + tr_) * 256 + (k1) + ((sl_ ^ (tr_ & 7)) * 8)], \
            &(dst)[s_ * 8]); }
#define STAGE_B(q, k1, dst)                                                     \
    { int s_ = (q) * 512 + t; int tr_ = s_ >> 3, sl_ = s_ & 7;                  \
      gld16(&Kp[(size_t)(jt * 256 + tr_) * 256 + (k1) + ((sl_ ^ (tr_ & 7)) * 8)], \
            &(dst)[s_ * 8]); }

    {
        short* Ad = As0; short* Bd = Bs0;
        STAGE_A(0, 0, Ad); STAGE_A(1, 0, Ad); STAGE_A(2, 0, Ad); STAGE_A(3, 0, Ad);
        STAGE_B(0, 0, Bd); STAGE_B(1, 0, Bd); STAGE_B(2, 0, Bd); STAGE_B(3, 0, Bd);
    }
    asm volatile("s_waitcnt vmcnt(0)" ::: "memory");
    __builtin_amdgcn_sched_barrier(0);
    __builtin_amdgcn_s_barrier();

    for (int kt = 0; kt < 4; ++kt) {
        const int cur = kt & 1;
        const short* Ac = As0 + cur * 16384;
        const short* Bc = Bs0 + cur * 16384;
        short* Ad = As0 + (cur ^ 1) * 16384;
        short* Bd = Bs0 + (cur ^ 1) * 16384;
        const int k1 = (kt + 1) * 64;
#pragma unroll
        for (int p = 0; p < 4; ++p) {
            const int mh = p >> 1, nh = p & 1;
            bf16x8 aF[4][2], bF[2][2];
#pragma unroll
            for (int m = 0; m < 4; ++m)
#pragma unroll
                for (int ks = 0; ks < 2; ++ks) {
                    int row = wr * 128 + mh * 64 + m * 16 + lr;
                    aF[m][ks] = *(const bf16x8*)
                        &Ac[row * 64 + (((ks * 4 + lg4) ^ (lr & 7)) * 8)];
                }
#pragma unroll
            for (int n = 0; n < 2; ++n)
#pragma unroll
                for (int ks = 0; ks < 2; ++ks) {
                    int row = wc * 64 + (nh * 2 + n) * 16 + lr;
                    bF[n][ks] = *(const bf16x8*)
                        &Bc[row * 64 + (((ks * 4 + lg4) ^ (lr & 7)) * 8)];
                }
            if (kt < 3) {
                if (p == 0)      { STAGE_A(0, k1, Ad); STAGE_A(2, k1, Ad); }
                else if (p == 1) { STAGE_B(0, k1, Bd); STAGE_B(1, k1, Bd); }
                else if (p == 2) { STAGE_B(2, k1, Bd); STAGE_B(3, k1, Bd); }
                else             { STAGE_A(1, k1, Ad); STAGE_A(3, k1, Ad); }
            }
            if (p == 1) {
                if (kt < 3) asm volatile("s_waitcnt vmcnt(4)" ::: "memory");
                else        asm volatile("s_waitcnt vmcnt(0)" ::: "memory");
            } else if (p == 3 && kt < 3) {
                asm volatile("s_waitcnt vmcnt(2)" ::: "memory");
            }
            __builtin_amdgcn_sched_barrier(0);
            __builtin_amdgcn_s_barrier();
            asm volatile("s_waitcnt lgkmcnt(0)" ::: "memory");
            __builtin_amdgcn_sched_barrier(0);
            __builtin_amdgcn_s_setprio(1);
#pragma unroll
            for (int ks = 0; ks < 2; ++ks)
#pragma unroll
                for (int m = 0; m < 4; ++m)
#pragma unroll
                    for (int n = 0; n < 2; ++n)
                        acc[mh * 4 + m][nh * 2 + n] =
                            __builtin_amdgcn_mfma_f32_16x16x32_bf16(
                                aF[m][ks], bF[n][ks], acc[mh * 4 + m][nh * 2 + n],
                                0, 0, 0);
            __builtin_amdgcn_s_setprio(0);
        }
    }
#undef STAGE_A
#undef STAGE_B

    // ---- epilogue ----
    // All frag ds_reads completed (each wave passed lgkmcnt(0) pre-MFMA);
    // barrier, then reuse SMEM as per-wave 64x64 transpose buffers (stride 66).
    __syncthreads();
    short* wbuf = SMEM + wid * 4224;               // 64 x 66 shorts = 8.25 KB
    short* Pp = Pe + ((size_t)bh << 20);
    const int rowbase = it * 256 + wr * 128;
    const int colbase = jt * 256 + wc * 64;
    int vmv[4];
#pragma unroll
    for (int nf = 0; nf < 4; ++nf)
        vmv[nf] = vm[(b << 10) + colbase + nf * 16 + lr];
    float zacc[8][4] = {};
#pragma unroll
    for (int half = 0; half < 2; ++half) {
#pragma unroll
        for (int mq = 0; mq < 4; ++mq) {
            const int mf = half * 4 + mq;
#pragma unroll
            for (int nf = 0; nf < 4; ++nf) {
                const int col = colbase + nf * 16 + lr;
#pragma unroll
                for (int r = 0; r < 4; ++r) {
                    const int row = rowbase + mf * 16 + lg4 * 4 + r;
                    float e = __expf(acc[mf][nf][r]);
                    wbuf[(mq * 16 + lg4 * 4 + r) * 66 + nf * 16 + lr] = f2bf(e);
                    zacc[mf][r] += (vmv[nf] && (col > row)) ? e : 0.f;
                }
            }
        }
        // flush 64 rows: 8 x (b128 LDS read + 16B/lane coalesced global store)
#pragma unroll
        for (int c = 0; c < 8; ++c) {
            const int rrow = c * 8 + (lane >> 3);
            bf16x8 v = *(const bf16x8*)&wbuf[rrow * 66 + (lane & 7) * 8];
            const int grow = rowbase + half * 64 + rrow;
            if (colbase + 63 > grow)               // skip rows with no live j
                *(bf16x8*)&Pp[(size_t)grow * 1024 + colbase + (lane & 7) * 8] = v;
        }
    }
#pragma unroll
    for (int mf = 0; mf < 8; ++mf)
#pragma unroll
        for (int r = 0; r < 4; ++r) {
            zacc[mf][r] += __shfl_xor(zacc[mf][r], 1);
            zacc[mf][r] += __shfl_xor(zacc[mf][r], 2);
            zacc[mf][r] += __shfl_xor(zacc[mf][r], 4);
            zacc[mf][r] += __shfl_xor(zacc[mf][r], 8);
        }
    if (lr == 0) {
        float* Zs = Zp + (size_t)(jt * 4 + wc) * 32768 + bh * 1024;
#pragma unroll
        for (int mf = 0; mf < 8; ++mf)
#pragma unroll
            for (int r = 0; r < 4; ++r)
                Zs[rowbase + mf * 16 + lg4 * 4 + r] = zacc[mf][r];
    }
}

// ---- 5. ecF[(b,i)][h] = exp(lg)/Z; sum only written Zp slices (jt>=i>>8) ----
__global__ LB void k_c(const float* __restrict__ lgA, const float* __restrict__ Zp,
                       float* __restrict__ ecF) {
    int idx = blockIdx.x * 256 + threadIdx.x;      // 8192 = b*1024+i
    int b = idx >> 10, i = idx & 1023;
    int sl0 = (i >> 8) * 4;
    float4 lg = *(const float4*)&lgA[idx * 4];
    float4 o;
#pragma unroll
    for (int h = 0; h < 4; ++h) {
        int base = (b * 4 + h) * 1024 + i;
        float Zv = 0.f;
        for (int sl = sl0; sl < 16; ++sl) Zv += Zp[sl * 32768 + base];
        float lgv = (h == 0) ? lg.x : (h == 1) ? lg.y : (h == 2) ? lg.z : lg.w;
        float e = (Zv > 0.f) ? __expf(lgv) / Zv : 0.f;
        if (h == 0) o.x = e; else if (h == 1) o.y = e;
        else if (h == 2) o.z = e; else o.w = e;
    }
    *(float4*)&ecF[idx * 4] = o;
}

// ---- 6. streaming epilogue: out = alive ? log(dot(P, ec)) : -1e9 ------------
__global__ LB void k_final(const short* __restrict__ Pe, const int* __restrict__ vm,
                           const float* __restrict__ ecF, float* __restrict__ out) {
    const int blk = blockIdx.x;                    // b*1024 + i
    const int b = blk >> 10, i = blk & 1023;
    const int j0 = threadIdx.x * 4;
    float4 o = {-1.0e9f, -1.0e9f, -1.0e9f, -1.0e9f};
    if (j0 + 3 > i) {
        float4 ec = *(const float4*)&ecF[blk * 4];
        int4 v4 = *(const int4*)&vm[(b << 10) + j0];
        const size_t off = ((size_t)(i) << 10) + j0;
        bf16x4 p0 = *(const bf16x4*)&Pe[(((size_t)(b * 4 + 0)) << 20) + off];
        bf16x4 p1 = *(const bf16x4*)&Pe[(((size_t)(b * 4 + 1)) << 20) + off];
        bf16x4 p2 = *(const bf16x4*)&Pe[(((size_t)(b * 4 + 2)) << 20) + off];
        bf16x4 p3 = *(const bf16x4*)&Pe[(((size_t)(b * 4 + 3)) << 20) + off];
        float a0 = bf2f(p0[0]) * ec.x + bf2f(p1[0]) * ec.y
                 + bf2f(p2[0]) * ec.z + bf2f(p3[0]) * ec.w;
        float a1 = bf2f(p0[1]) * ec.x + bf2f(p1[1]) * ec.y
                 + bf2f(p2[1]) * ec.z + bf2f(p3[1]) * ec.w;
        float a2 = bf2f(p0[2]) * ec.x + bf2f(p1[2]) * ec.y
                 + bf2f(p2[2]) * ec.z + bf2f(p3[2]) * ec.w;
        float a3 = bf2f(p0[3]) * ec.x + bf2f(p1[3]) * ec.y
                 + bf2f(p2[3]) * ec.z + bf2f(p3[3]) * ec.w;
        o.x = (v4.x && (j0 + 0 > i)) ? __logf(a0) : -1.0e9f;
        o.y = (v4.y && (j0 + 1 > i)) ? __logf(a1) : -1.0e9f;
        o.z = (v4.z && (j0 + 2 > i)) ? __logf(a2) : -1.0e9f;
        o.w = (v4.w && (j0 + 3 > i)) ? __logf(a3) : -1.0e9f;
    }
    *(float4*)&out[((size_t)blk << 10) + j0] = o;
}

// ---------------------------------------------------------------------------
extern "C" void kernel_launch(void* const* d_in, const int* in_sizes, int n_in,
                              void* d_out, int out_size, void* d_ws, size_t ws_size,
                              hipStream_t stream) {
    const float* features = (const float*)d_in[0];
    const int*   vmask    = (const int*)d_in[1];
    const float* Wq       = (const float*)d_in[2];
    const float* bq       = (const float*)d_in[3];
    const float* Wk       = (const float*)d_in[4];
    const float* bk       = (const float*)d_in[5];
    const float* Wg       = (const float*)d_in[6];
    const float* bg       = (const float*)d_in[7];
    float* out = (float*)d_out;

    // ws carve (~103 MB peak). Pe overlaps Xb+Wt (dead before k_sc).
    short* Pe = (short*)d_ws;                  // [32 bh][1024 i][1024 j] bf16 = 67 MB
    short* Xb = (short*)d_ws;                  // [8192][1024] bf16 (dead after k_gemm)
    short* Wt = Xb + 8388608;                  // [2048][1024] bf16 (dead after k_gemm)
    short* Qb = Pe + 33554432;                 // [32 bh][1024 i][256 d] bf16 (scaled 1/16)
    short* Kb = Qb + 8388608;                  // [32 bh][1024 j][256 d] bf16
    float* lgA = (float*)(Kb + 8388608);       // [8192][4]
    float* Zp  = lgA + 32768;                  // [16 slice][32 bh][1024 i]
    float* ecF = Zp + 524288;                  // [8192][4]

    k_prep<<<2048, 256, 0, stream>>>(features, Wg, bg, Xb, lgA);
    k_cvt_w<<<dim3(64, 32), dim3(32, 8), 0, stream>>>(Wq, Wk, Wt);
    k_gemm<<<256, 512, 0, stream>>>(Xb, Wt, bq, bk, Qb, Kb);
    k_sc<<<320, 512, 0, stream>>>(Qb, Kb, vmask, Pe, Zp);
    k_c<<<32, 256, 0, stream>>>(lgA, Zp, ecF);
    k_final<<<8192, 256, 0, stream>>>(Pe, vmask, ecF, out);
}